// Round 1
// baseline (546.898 us; speedup 1.0000x reference)
//
#include <hip/hip_runtime.h>

#define NUM_ATOMS 40000
#define NUM_EDGES 640000
// FAN_IN = NFM = FAN_OUT = 128

// clang ext-vector types so __builtin_nontemporal_load works on 8B loads
typedef float f2v __attribute__((ext_vector_type(2)));

// ---------------------------------------------------------------------------
// Kernel R: CSR row offsets from sorted seg_i.
// rs[i] = lower_bound(seg_i, i) for i in [0, NUM_ATOMS]. rs[NUM_ATOMS] = NUM_EDGES.
// ---------------------------------------------------------------------------
__global__ void k_rowstart(const int* __restrict__ seg, int* __restrict__ rs) {
  const int i = blockIdx.x * blockDim.x + threadIdx.x;
  if (i > NUM_ATOMS) return;
  int lo = 0, hi = NUM_EDGES;
  while (lo < hi) {
    const int mid = (lo + hi) >> 1;
    if (seg[mid] < i) lo = mid + 1; else hi = mid;
  }
  rs[i] = lo;
}

// ---------------------------------------------------------------------------
// Kernel G: out[M][128] = A[M][128] @ W[128][128] (+ bias)   fp32 vector GEMM
// (unchanged — ~15-20 us each; conv is this round's single variable)
// ---------------------------------------------------------------------------
__global__ __launch_bounds__(512, 2) void k_gemm128(
    const float* __restrict__ A, const float* __restrict__ W,
    const float* __restrict__ bias, float* __restrict__ out) {
  __shared__ float AT[128 * 128];  // [k][m]
  __shared__ float Wl[128 * 128];  // [k][n]
  const int t = threadIdx.x;
  const int m0 = blockIdx.x * 128;

  {
    const float4* Wg = (const float4*)W;
    float4* Ws = (float4*)Wl;
#pragma unroll
    for (int i = 0; i < 8; ++i) Ws[t + i * 512] = Wg[t + i * 512];
  }
  {
    const int m = t & 127;
    const int kq = t >> 7;  // 0..3
    int mg = m0 + m;
    if (mg >= NUM_ATOMS) mg = NUM_ATOMS - 1;  // clamp (stores are guarded)
    const float4* ag = (const float4*)(A + (size_t)mg * 128);
#pragma unroll
    for (int i = 0; i < 8; ++i) {
      const int k4 = kq + i * 4;  // 0..31
      const float4 v = ag[k4];
      const int k = k4 * 4;
      AT[(k + 0) * 128 + m] = v.x;
      AT[(k + 1) * 128 + m] = v.y;
      AT[(k + 2) * 128 + m] = v.z;
      AT[(k + 3) * 128 + m] = v.w;
    }
  }
  __syncthreads();

  const int tx = t & 31;
  const int ty = t >> 5;

  float binit[4] = {0.f, 0.f, 0.f, 0.f};
  if (bias != nullptr) {
    const float2 bb0 = ((const float2*)bias)[tx];
    const float2 bb1 = ((const float2*)bias)[32 + tx];
    binit[0] = bb0.x; binit[1] = bb0.y; binit[2] = bb1.x; binit[3] = bb1.y;
  }
  float acc[8][4];
#pragma unroll
  for (int i = 0; i < 8; ++i)
#pragma unroll
    for (int j = 0; j < 4; ++j) acc[i][j] = binit[j];

#pragma unroll 4
  for (int k = 0; k < 128; ++k) {
    const float4 a0 = *(const float4*)&AT[k * 128 + 4 * ty];
    const float4 a1 = *(const float4*)&AT[k * 128 + 64 + 4 * ty];
    const float2 b0 = *(const float2*)&Wl[k * 128 + 2 * tx];
    const float2 b1 = *(const float2*)&Wl[k * 128 + 64 + 2 * tx];
    const float av[8] = {a0.x, a0.y, a0.z, a0.w, a1.x, a1.y, a1.z, a1.w};
    const float bv[4] = {b0.x, b0.y, b1.x, b1.y};
#pragma unroll
    for (int i = 0; i < 8; ++i)
#pragma unroll
      for (int j = 0; j < 4; ++j) acc[i][j] += av[i] * bv[j];
  }

#pragma unroll
  for (int i = 0; i < 8; ++i) {
    const int m = (i < 4) ? (4 * ty + i) : (64 + 4 * ty + (i - 4));
    const int mg = m0 + m;
    if (mg < NUM_ATOMS) {
      float2* o = (float2*)(out + (size_t)mg * 128);
      o[tx]      = make_float2(acc[i][0], acc[i][1]);
      o[32 + tx] = make_float2(acc[i][2], acc[i][3]);
    }
  }
}

// ---------------------------------------------------------------------------
// Kernel C: conv[a] = sum_{e in [rs[a],rs[a+1])} w_ij[e] * f[idx_j[e]]
// One wave per atom. Per <=32-edge chunk: preload ALL w-rows and f-rows into
// register arrays (up to 64 independent 512B loads = 16 KB in flight per
// wave, no intervening waits), then one wait + FMA burst.
//
// R3 change (single variable): w_ij and idx_j are ZERO-REUSE streams totaling
// ~330 MB/iter — larger than the 256 MB Infinity Cache — so with normal loads
// the stream washes the LLC every iteration and evicts the 20.5 MB f table.
// The f gathers then miss to HBM as random 512B requests (DRAM-page-thrash
// regime, far below the 6.3 TB/s streaming ceiling). Loading the streams with
// __builtin_nontemporal_load (gfx950 `nt` flag: evict-first / no LLC
// allocation) keeps f LLC-resident so gathers hit in-cache.
// Guards at granularity 8 with clamped index as before; lane l owns channels
// 2l, 2l+1.
// ---------------------------------------------------------------------------
__global__ __launch_bounds__(256) void k_conv(
    const float* __restrict__ f, const float* __restrict__ w_ij,
    const int* __restrict__ idx_j, const int* __restrict__ rs,
    float* __restrict__ conv) {
  const int wv = threadIdx.x >> 6;
  const int l = threadIdx.x & 63;
  const int a = blockIdx.x * 4 + wv;  // 40000 = 10000 * 4, always in range

  const int e0 = rs[a];
  const int e1 = rs[a + 1];
  float accx = 0.f, accy = 0.f;

  for (int base = e0; base < e1; base += 32) {
    const int n = min(32, e1 - base);  // wave-uniform
    const int nm1 = n - 1;
    // one coalesced idx load for the chunk (lanes >= n masked off); NT: the
    // idx stream is read exactly once per iteration.
    int j = 0;
    if (l < n) j = __builtin_nontemporal_load(idx_j + base + l);

    f2v wr[32];
    float2 fr[32];
    // ---- preload w rows (independent of idx); NT streaming loads ----
#pragma unroll
    for (int g = 0; g < 4; ++g) {
      if (n > g * 8) {
#pragma unroll
        for (int k = g * 8; k < g * 8 + 8; ++k) {
          const int kk = min(k, nm1);
          wr[k] = __builtin_nontemporal_load(
              (const f2v*)(w_ij + (size_t)(base + kk) * 128) + l);
        }
      }
    }
    // ---- preload f rows (depend only on the single idx load) ----
    // NORMAL loads: f is the reused 20.5 MB table we want cached.
#pragma unroll
    for (int g = 0; g < 4; ++g) {
      if (n > g * 8) {
#pragma unroll
        for (int k = g * 8; k < g * 8 + 8; ++k) {
          const int kk = min(k, nm1);
          const int jk = __shfl(j, kk);
          fr[k] = ((const float2*)(f + (size_t)jk * 128))[l];
        }
      }
    }
    // ---- FMA burst ----
#pragma unroll
    for (int g = 0; g < 4; ++g) {
      if (n > g * 8) {
#pragma unroll
        for (int k = g * 8; k < g * 8 + 8; ++k) {
          if (k < n) {
            accx += wr[k].x * fr[k].x;
            accy += wr[k].y * fr[k].y;
          }
        }
      }
    }
  }
  // coalesced float2 store; zero-edge atoms correctly write 0
  ((float2*)(conv + (size_t)a * 128))[l] = make_float2(accx, accy);
}

// ---------------------------------------------------------------------------
extern "C" void kernel_launch(void* const* d_in, const int* in_sizes, int n_in,
                              void* d_out, int out_size, void* d_ws, size_t ws_size,
                              hipStream_t stream) {
  const float* x    = (const float*)d_in[0];
  const float* w_ij = (const float*)d_in[1];
  const int*   seg  = (const int*)d_in[2];
  const int*   idxj = (const int*)d_in[3];
  // d_in[4] = seg_i_sum scalar (== NUM_ATOMS, hardcoded)
  const float* Win  = (const float*)d_in[5];
  const float* Wout = (const float*)d_in[6];
  const float* bout = (const float*)d_in[7];
  float* out = (float*)d_out;

  // workspace: f (20.48 MB) | conv (20.48 MB) | rs (40001 i32)
  float* f    = (float*)d_ws;
  float* conv = (float*)((char*)d_ws + (size_t)NUM_ATOMS * 128 * sizeof(float));
  int*   rs   = (int*)((char*)d_ws + 2 * (size_t)NUM_ATOMS * 128 * sizeof(float));

  k_rowstart<<<(NUM_ATOMS + 1 + 255) / 256, 256, 0, stream>>>(seg, rs);
  k_gemm128<<<(NUM_ATOMS + 127) / 128, 512, 0, stream>>>(x, Win, nullptr, f);
  k_conv<<<NUM_ATOMS / 4, 256, 0, stream>>>(f, w_ij, idxj, rs, conv);
  k_gemm128<<<(NUM_ATOMS + 127) / 128, 512, 0, stream>>>(conv, Wout, bout, out);
}